// Round 7
// baseline (1326.306 us; speedup 1.0000x reference)
//
#include <hip/hip_runtime.h>
#include <math.h>

// GRNNTransformGated — round 7: round-6 MFMA kernel +
//  (A) LDS 57.9KB -> 48KB: hacc aliases zb_hi (dead by combine) -> 3 blocks/CU
//  (B) intermediate h levels stored as pre-split bf16 hi/lo (A=ws, B=d_out
//      scratch; level 0 writes f32 to d_out). Gather = pure 16B loads, no
//      split VALU; h HBM traffic halved. Numerics identical (same split of
//      the same f32 value, done once at writer instead of twice at readers).
//
// ws layout: [0,8M) A_hi ; [8M,16M) A_lo ; [16M,+448K) split weights.
// Parity: buf(k) = A if k odd, B(d_out scratch) if k even; level 0 -> f32 d_out.

#define N_NODES 65536
#define FEAT 7
#define H 64
#define MT 32            // nodes per block (2 m-tiles of 16)
#define BLK 256          // 4 waves

typedef __attribute__((ext_vector_type(8))) short bf16x8;
typedef __attribute__((ext_vector_type(4))) short short4v;
typedef __attribute__((ext_vector_type(4))) float f32x4;

__device__ __forceinline__ void split_bf16(float x, short& hi, short& lo) {
    unsigned u = __float_as_uint(x);
    unsigned r = (u + 0x7fffu + ((u >> 16) & 1u)) >> 16;   // RNE to bf16
    hi = (short)r;
    float res = x - __uint_as_float(r << 16);
    unsigned u2 = __float_as_uint(res);
    unsigned r2 = (u2 + 0x7fffu + ((u2 >> 16) & 1u)) >> 16;
    lo = (short)r2;
}
__device__ __forceinline__ float bf2f(short h) {
    return __uint_as_float(((unsigned)(unsigned short)h) << 16);
}
// XOR-swizzled LDS index: 8-elem (16B) chunks, chunk ^= row&7
__device__ __forceinline__ int zbidx(int row, int col) {   // 192-wide rows
    return row * 192 + ((((col >> 3) ^ (row & 7)) << 3) | (col & 7));
}
__device__ __forceinline__ int zaidx(int row, int col) {   // 64-wide rows
    return row * 64 + ((((col >> 3) ^ (row & 7)) << 3) | (col & 7));
}

#define MFMA3(acc, ah, al, bh8, bl8)                                              \
    acc = __builtin_amdgcn_mfma_f32_16x16x32_bf16(al, bh8, acc, 0, 0, 0);         \
    acc = __builtin_amdgcn_mfma_f32_16x16x32_bf16(ah, bl8, acc, 0, 0, 0);         \
    acc = __builtin_amdgcn_mfma_f32_16x16x32_bf16(ah, bh8, acc, 0, 0, 0);

// ---------------- weight prep: fp32 -> pre-arranged bf16 hi/lo fragments -------
// layout per (nt,s): 1024 shorts = [hi: 64 lanes x 8][lo: 64 lanes x 8]
// lane l holds W[nt*16 + (l&15)][s*32 + (l>>4)*8 + e]
__global__ __launch_bounds__(256) void grnn_prep(
    const float* __restrict__ Wr, const float* __restrict__ Wh,
    const float* __restrict__ Wz, short* __restrict__ wsp)
{
    int job = blockIdx.x * 4 + (threadIdx.x >> 6);   // 224 jobs
    int lane = threadIdx.x & 63;
    const float* src; int K, t, s; short* dst;
    short* ws_wh = wsp + 72 * 1024;
    short* ws_wz = wsp + 96 * 1024;
    if (job < 72)       { t = job / 6;            s = job % 6;        K = 192; src = Wr; dst = wsp   + job * 1024; }
    else if (job < 96)  { int j = job - 72; t = j / 6; s = j % 6;     K = 192; src = Wh; dst = ws_wh + j * 1024; }
    else                { int j = job - 96; t = j / 8; s = j % 8;     K = 256; src = Wz; dst = ws_wz + j * 1024; }
    int i  = t * 16 + (lane & 15);
    int k0 = s * 32 + (lane >> 4) * 8;
    const float* p = src + (size_t)i * K + k0;
    bf16x8 hi, lo;
#pragma unroll
    for (int e = 0; e < 8; ++e) { short h, l; split_bf16(p[e], h, l); hi[e] = h; lo[e] = l; }
    *(bf16x8*)(dst + lane * 8) = hi;
    *(bf16x8*)(dst + 512 + lane * 8) = lo;
}

// ---------------- leaf embed (level 15) -> hi/lo buffers ----------------------
__global__ __launch_bounds__(BLK) void grnn_leaf_bf(
    const float* __restrict__ contents, const float* __restrict__ Wu,
    const float* __restrict__ bu, short* __restrict__ hi_out, short* __restrict__ lo_out)
{
    int t = blockIdx.x * BLK + threadIdx.x;
    int node = t >> 6;
    int j = t & 63;
    const float* c = contents + (size_t)15 * N_NODES * FEAT + (size_t)node * FEAT;
    float acc = bu[j];
#pragma unroll
    for (int f = 0; f < FEAT; ++f) acc += c[f] * Wu[j * FEAT + f];
    short h, l; split_bf16(fmaxf(acc, 0.f), h, l);
    hi_out[t] = h;
    lo_out[t] = l;
}

// legacy f32 leaf (fallback path only)
__global__ __launch_bounds__(BLK) void grnn_leaf_kernel(
    const float* __restrict__ contents, const float* __restrict__ Wu,
    const float* __restrict__ bu, float* __restrict__ h_out)
{
    int t = blockIdx.x * BLK + threadIdx.x;
    int node = t >> 6;
    int j = t & 63;
    const float* c = contents + (size_t)15 * N_NODES * FEAT + (size_t)node * FEAT;
    float acc = bu[j];
#pragma unroll
    for (int f = 0; f < FEAT; ++f) acc += c[f] * Wu[j * FEAT + f];
    h_out[t] = fmaxf(acc, 0.f);
}

// ---------------- fused MFMA step kernel --------------------------------------
__global__ __launch_bounds__(BLK) void grnn_step_mfma(
    const float* __restrict__ contents_k, const int* __restrict__ children_k,
    const short* __restrict__ hin_hi, const short* __restrict__ hin_lo,
    const float* __restrict__ Wu, const float* __restrict__ bu,
    const float* __restrict__ br, const float* __restrict__ bh,
    const float* __restrict__ bz,
    const short* __restrict__ wsp,
    short* __restrict__ hout_hi, short* __restrict__ hout_lo,
    float* __restrict__ out_f32, int is_final)
{
    // 48 KiB pool: [zb_hi | zb_lo | ub0 | ub1], hacc aliases zb_hi (dead then)
    __shared__ __align__(16) short smem[4 * MT * 192];
    short* zb_hi = smem;                 // hhu hi
    short* zb_lo = smem + MT * 192;      // hhu lo
    short* ub0   = smem + 2 * MT * 192;  // rh hi; head reused as h_H hi (za)
    short* ub1   = smem + 3 * MT * 192;  // rh lo; head reused as h_H lo
    float* hacc  = (float*)smem;         // combine accumulator (aliases zb_hi)

    const int tid = threadIdx.x;
    const int node0 = blockIdx.x * MT;
    const int wv = tid >> 6, lane = tid & 63, lr = lane & 15, lh = lane >> 4;
    const short* wr_s = wsp;
    const short* wh_s = wsp + 72 * 1024;
    const short* wz_s = wsp + 96 * 1024;
    const f32x4 z4 = {0.f, 0.f, 0.f, 0.f};

    // ---- gather h_L / h_R: pure 16B loads of pre-split hi/lo (no VALU) -------
    {
        int row = tid >> 2, q = tid & 3;            // row 0..63
        int nd = row >> 1, side = row & 1;
        int child = children_k[(size_t)(node0 + nd) * 2 + side];
        const bf16x8* srch = (const bf16x8*)(hin_hi + (size_t)child * H + q * 16);
        const bf16x8* srcl = (const bf16x8*)(hin_lo + (size_t)child * H + q * 16);
        int col0 = side * 64 + q * 16;
        int i0 = zbidx(nd, col0);
        int i1 = zbidx(nd, col0 + 8);
        *(bf16x8*)&zb_hi[i0] = srch[0];
        *(bf16x8*)&zb_hi[i1] = srch[1];
        *(bf16x8*)&zb_lo[i0] = srcl[0];
        *(bf16x8*)&zb_lo[i1] = srcl[1];
    }
    // ---- u_k = relu(contents @ Wu.T + bu) -> zb cols 128..191 ----------------
    {
        int nd = tid >> 3, j0 = (tid & 7) * 8;
        float c[FEAT];
#pragma unroll
        for (int f = 0; f < FEAT; ++f) c[f] = contents_k[(size_t)(node0 + nd) * FEAT + f];
        bf16x8 hv, lv;
#pragma unroll
        for (int jj = 0; jj < 8; ++jj) {
            int j = j0 + jj;
            float a = bu[j];
#pragma unroll
            for (int f = 0; f < FEAT; ++f) a += c[f] * Wu[j * FEAT + f];
            a = fmaxf(a, 0.f);
            short h, l; split_bf16(a, h, l); hv[jj] = h; lv[jj] = l;
        }
        int idx = zbidx(nd, 128 + j0);
        *(bf16x8*)&zb_hi[idx] = hv;
        *(bf16x8*)&zb_lo[idx] = lv;
    }
    __syncthreads();

    // ---- GEMM1: r-logits = hhu @ Wr.T ; wave wv owns n-tiles {3wv..3wv+2} ----
    f32x4 acc1[2][3];
#pragma unroll
    for (int mi = 0; mi < 2; ++mi)
#pragma unroll
        for (int ni = 0; ni < 3; ++ni) acc1[mi][ni] = z4;
    for (int s = 0; s < 6; ++s) {
        bf16x8 ah[2], al[2];
#pragma unroll
        for (int mi = 0; mi < 2; ++mi) {
            int idx = zbidx(mi * 16 + lr, s * 32 + lh * 8);
            ah[mi] = *(const bf16x8*)&zb_hi[idx];
            al[mi] = *(const bf16x8*)&zb_lo[idx];
        }
#pragma unroll
        for (int ni = 0; ni < 3; ++ni) {
            const short* bp = wr_s + ((3 * wv + ni) * 6 + s) * 1024;
            bf16x8 bh8 = *(const bf16x8*)(bp + lane * 8);
            bf16x8 bl8 = *(const bf16x8*)(bp + 512 + lane * 8);
#pragma unroll
            for (int mi = 0; mi < 2; ++mi) { MFMA3(acc1[mi][ni], ah[mi], al[mi], bh8, bl8); }
        }
    }
    // epilogue1: sigmoid gate, rh = r*hhu -> ub (swizzled)
#pragma unroll
    for (int ni = 0; ni < 3; ++ni) {
        int i = (3 * wv + ni) * 16 + lr;
        float brv = br[i];
#pragma unroll
        for (int mi = 0; mi < 2; ++mi) {
#pragma unroll
            for (int r = 0; r < 4; ++r) {
                int nd = mi * 16 + lh * 4 + r;
                float v = acc1[mi][ni][r] + brv;
                float sg = 1.f / (1.f + __expf(-v));
                int xi = zbidx(nd, i);
                float x = bf2f(zb_hi[xi]) + bf2f(zb_lo[xi]);
                short h, l; split_bf16(sg * x, h, l);
                ub0[xi] = h;
                ub1[xi] = l;
            }
        }
    }
    __syncthreads();

    // ---- GEMM2: h_H = relu(rh @ Wh.T + bh) ; wave wv owns n-tile wv ----------
    f32x4 acc2[2] = {z4, z4};
    for (int s = 0; s < 6; ++s) {
        bf16x8 ah[2], al[2];
#pragma unroll
        for (int mi = 0; mi < 2; ++mi) {
            int idx = zbidx(mi * 16 + lr, s * 32 + lh * 8);
            ah[mi] = *(const bf16x8*)&ub0[idx];
            al[mi] = *(const bf16x8*)&ub1[idx];
        }
        const short* bp = wh_s + (wv * 6 + s) * 1024;
        bf16x8 bh8 = *(const bf16x8*)(bp + lane * 8);
        bf16x8 bl8 = *(const bf16x8*)(bp + 512 + lane * 8);
#pragma unroll
        for (int mi = 0; mi < 2; ++mi) { MFMA3(acc2[mi], ah[mi], al[mi], bh8, bl8); }
    }
    __syncthreads();     // all rh reads done before za overwrites ub head
    {
        int j = wv * 16 + lr;
        float bhv = bh[j];
#pragma unroll
        for (int mi = 0; mi < 2; ++mi) {
#pragma unroll
            for (int r = 0; r < 4; ++r) {
                int nd = mi * 16 + lh * 4 + r;
                float v = fmaxf(acc2[mi][r] + bhv, 0.f);
                short h, l; split_bf16(v, h, l);
                int idx = zaidx(nd, j);
                ub0[idx] = h;   // za_hi
                ub1[idx] = l;   // za_lo
            }
        }
    }
    __syncthreads();

    // ---- GEMM3: z = [h_H|hhu] @ Wz.T ; wave wv = gate, n-tiles {4wv..4wv+3} --
    f32x4 acc3[2][4];
#pragma unroll
    for (int mi = 0; mi < 2; ++mi)
#pragma unroll
        for (int jh = 0; jh < 4; ++jh) acc3[mi][jh] = z4;
    for (int s = 0; s < 8; ++s) {
        bf16x8 ah[2], al[2];
#pragma unroll
        for (int mi = 0; mi < 2; ++mi) {
            int row = mi * 16 + lr;
            if (s < 2) {
                int idx = zaidx(row, s * 32 + lh * 8);
                ah[mi] = *(const bf16x8*)&ub0[idx];
                al[mi] = *(const bf16x8*)&ub1[idx];
            } else {
                int idx = zbidx(row, s * 32 + lh * 8 - 64);
                ah[mi] = *(const bf16x8*)&zb_hi[idx];
                al[mi] = *(const bf16x8*)&zb_lo[idx];
            }
        }
#pragma unroll
        for (int jh = 0; jh < 4; ++jh) {
            const short* bp = wz_s + ((wv * 4 + jh) * 8 + s) * 1024;
            bf16x8 bh8 = *(const bf16x8*)(bp + lane * 8);
            bf16x8 bl8 = *(const bf16x8*)(bp + 512 + lane * 8);
#pragma unroll
            for (int mi = 0; mi < 2; ++mi) { MFMA3(acc3[mi][jh], ah[mi], al[mi], bh8, bl8); }
        }
    }
    // ---- epilogue3: per-gate softmax over 64 j (in-wave) + gated combine -----
    float bzv[4];
#pragma unroll
    for (int jh = 0; jh < 4; ++jh) bzv[jh] = bz[wv * 64 + jh * 16 + lr];
    float contrib[2][4][4];
#pragma unroll
    for (int mi = 0; mi < 2; ++mi) {
#pragma unroll
        for (int r = 0; r < 4; ++r) {
            float v0 = acc3[mi][0][r] + bzv[0];
            float v1 = acc3[mi][1][r] + bzv[1];
            float v2 = acc3[mi][2][r] + bzv[2];
            float v3 = acc3[mi][3][r] + bzv[3];
            float mx = fmaxf(fmaxf(v0, v1), fmaxf(v2, v3));
            mx = fmaxf(mx, __shfl_xor(mx, 1));
            mx = fmaxf(mx, __shfl_xor(mx, 2));
            mx = fmaxf(mx, __shfl_xor(mx, 4));
            mx = fmaxf(mx, __shfl_xor(mx, 8));
            float e0 = __expf(v0 - mx), e1 = __expf(v1 - mx);
            float e2 = __expf(v2 - mx), e3 = __expf(v3 - mx);
            float sm = e0 + e1 + e2 + e3;
            sm += __shfl_xor(sm, 1);
            sm += __shfl_xor(sm, 2);
            sm += __shfl_xor(sm, 4);
            sm += __shfl_xor(sm, 8);
            float inv = 1.f / sm;
            int nd = mi * 16 + lh * 4 + r;
            float e[4] = {e0, e1, e2, e3};
#pragma unroll
            for (int jh = 0; jh < 4; ++jh) {
                int n = wv * 64 + jh * 16 + lr;
                float comp;
                if (wv == 0) {                     // wave-uniform branch
                    int idx = zaidx(nd, n);
                    comp = bf2f(ub0[idx]) + bf2f(ub1[idx]);
                } else {
                    int idx = zbidx(nd, n - 64);
                    comp = bf2f(zb_hi[idx]) + bf2f(zb_lo[idx]);
                }
                contrib[mi][jh][r] = e[jh] * inv * comp;
            }
        }
    }
    __syncthreads();     // all contrib reads of zb/ub done before hacc (alias) writes
    // phased deterministic accumulate (wave p = gate p), no atomics
    for (int p = 0; p < 4; ++p) {
        if (wv == p) {
#pragma unroll
            for (int mi = 0; mi < 2; ++mi)
#pragma unroll
                for (int r = 0; r < 4; ++r) {
                    int nd = mi * 16 + lh * 4 + r;
#pragma unroll
                    for (int jh = 0; jh < 4; ++jh) {
                        int hidx = nd * 68 + jh * 16 + lr;
                        if (p == 0) hacc[hidx] = contrib[mi][jh][r];
                        else        hacc[hidx] += contrib[mi][jh][r];
                    }
                }
        }
        __syncthreads();
    }
    // ---- write out: hi/lo for intermediate levels, f32 for level 0 -----------
    if (is_final) {
        for (int i = tid; i < MT * H; i += BLK) {
            int nd = i >> 6, j = i & 63;
            out_f32[(size_t)(node0 + nd) * H + j] = hacc[nd * 68 + j];
        }
    } else {
        for (int i = tid; i < MT * H; i += BLK) {
            int nd = i >> 6, j = i & 63;
            float v = hacc[nd * 68 + j];
            short h, l; split_bf16(v, h, l);
            size_t o = (size_t)(node0 + nd) * H + j;
            hout_hi[o] = h;
            hout_lo[o] = l;
        }
    }
}

// ---------------- round-1 fp32 fallback (used only if ws_size too small) ------
#define HP 196
#define HHP 68
#define ZP 260
#define NT1 16
__global__ __launch_bounds__(BLK) void grnn_step_v1(
    const float* __restrict__ contents_k, const int* __restrict__ children_k,
    const float* __restrict__ h_in,
    const float* __restrict__ Wu, const float* __restrict__ bu,
    const float* __restrict__ Wr, const float* __restrict__ br,
    const float* __restrict__ Wh, const float* __restrict__ bh,
    const float* __restrict__ Wz, const float* __restrict__ bz,
    float* __restrict__ h_out)
{
    __shared__ __align__(16) float hhu[NT1][HP];
    __shared__ __align__(16) float rh[NT1][HP];
    __shared__ __align__(16) float hH[NT1][HHP];
    __shared__ __align__(16) float zt[NT1][ZP];
    __shared__ float rden[NT1][4];
    const int tid = threadIdx.x;
    const int node0 = blockIdx.x * NT1;
    const int n = tid >> 4, c16 = tid & 15;
    {
        const float* cptr = contents_k + (size_t)(node0 + n) * FEAT;
        float cf[FEAT];
#pragma unroll
        for (int f = 0; f < FEAT; ++f) cf[f] = cptr[f];
#pragma unroll
        for (int jj = 0; jj < 4; ++jj) {
            int j = c16 + 16 * jj;
            float acc = bu[j];
#pragma unroll
            for (int f = 0; f < FEAT; ++f) acc += cf[f] * Wu[j * FEAT + f];
            hhu[n][128 + j] = fmaxf(acc, 0.f);
        }
#pragma unroll
        for (int it = 0; it < 8; ++it) {
            int t = tid + it * BLK;
            int nn = t >> 7, side = (t >> 6) & 1, j = t & 63;
            int child = children_k[(size_t)(node0 + nn) * 2 + side];
            hhu[nn][side * 64 + j] = h_in[(size_t)child * H + j];
        }
    }
    __syncthreads();
    {
        float acc[12];
#pragma unroll
        for (int ii = 0; ii < 12; ++ii) acc[ii] = br[c16 + 16 * ii];
        for (int k = 0; k < 192; k += 4) {
            float4 hv = *(const float4*)&hhu[n][k];
#pragma unroll
            for (int ii = 0; ii < 12; ++ii) {
                float4 w = *(const float4*)&Wr[(size_t)(c16 + 16 * ii) * 192 + k];
                acc[ii] += hv.x * w.x + hv.y * w.y + hv.z * w.z + hv.w * w.w;
            }
        }
#pragma unroll
        for (int ii = 0; ii < 12; ++ii) {
            int i = c16 + 16 * ii;
            rh[n][i] = (1.f / (1.f + __expf(-acc[ii]))) * hhu[n][i];
        }
    }
    __syncthreads();
    {
        float acc[4];
#pragma unroll
        for (int ii = 0; ii < 4; ++ii) acc[ii] = bh[c16 + 16 * ii];
        for (int k = 0; k < 192; k += 4) {
            float4 hv = *(const float4*)&rh[n][k];
#pragma unroll
            for (int ii = 0; ii < 4; ++ii) {
                float4 w = *(const float4*)&Wh[(size_t)(c16 + 16 * ii) * 192 + k];
                acc[ii] += hv.x * w.x + hv.y * w.y + hv.z * w.z + hv.w * w.w;
            }
        }
#pragma unroll
        for (int ii = 0; ii < 4; ++ii) hH[n][c16 + 16 * ii] = fmaxf(acc[ii], 0.f);
    }
    __syncthreads();
    {
        float acc[16];
#pragma unroll
        for (int ii = 0; ii < 16; ++ii) acc[ii] = bz[c16 + 16 * ii];
        for (int k = 0; k < 64; k += 4) {
            float4 hv = *(const float4*)&hH[n][k];
#pragma unroll
            for (int ii = 0; ii < 16; ++ii) {
                float4 w = *(const float4*)&Wz[(size_t)(c16 + 16 * ii) * 256 + k];
                acc[ii] += hv.x * w.x + hv.y * w.y + hv.z * w.z + hv.w * w.w;
            }
        }
        for (int k = 0; k < 192; k += 4) {
            float4 hv = *(const float4*)&hhu[n][k];
#pragma unroll
            for (int ii = 0; ii < 16; ++ii) {
                float4 w = *(const float4*)&Wz[(size_t)(c16 + 16 * ii) * 256 + 64 + k];
                acc[ii] += hv.x * w.x + hv.y * w.y + hv.z * w.z + hv.w * w.w;
            }
        }
#pragma unroll
        for (int ii = 0; ii < 16; ++ii) zt[n][c16 + 16 * ii] = acc[ii];
    }
    __syncthreads();
    {
        int sn = tid >> 4, g = (tid >> 2) & 3, q = tid & 3;
        float m = -INFINITY;
#pragma unroll
        for (int jj = 0; jj < 16; ++jj) m = fmaxf(m, zt[sn][g * 64 + q * 16 + jj]);
        m = fmaxf(m, __shfl_xor(m, 1));
        m = fmaxf(m, __shfl_xor(m, 2));
        float s = 0.f;
#pragma unroll
        for (int jj = 0; jj < 16; ++jj) {
            int idx = g * 64 + q * 16 + jj;
            float e = __expf(zt[sn][idx] - m);
            zt[sn][idx] = e;
            s += e;
        }
        s += __shfl_xor(s, 1);
        s += __shfl_xor(s, 2);
        if (q == 0) rden[sn][g] = 1.f / s;
    }
    __syncthreads();
    {
        size_t node = node0 + n;
#pragma unroll
        for (int jj = 0; jj < 4; ++jj) {
            int j = c16 + 16 * jj;
            float v = zt[n][j] * rden[n][0] * hH[n][j]
                    + zt[n][64 + j] * rden[n][1] * hhu[n][j]
                    + zt[n][128 + j] * rden[n][2] * hhu[n][64 + j]
                    + zt[n][192 + j] * rden[n][3] * hhu[n][128 + j];
            h_out[node * H + j] = v;
        }
    }
}

extern "C" void kernel_launch(void* const* d_in, const int* in_sizes, int n_in,
                              void* d_out, int out_size, void* d_ws, size_t ws_size,
                              hipStream_t stream) {
    const float* contents = (const float*)d_in[0];
    const int*   children = (const int*)d_in[1];
    const float* Wu = (const float*)d_in[2];
    const float* bu = (const float*)d_in[3];
    const float* Wr = (const float*)d_in[4];
    const float* br = (const float*)d_in[5];
    const float* Wh = (const float*)d_in[6];
    const float* bh = (const float*)d_in[7];
    const float* Wz = (const float*)d_in[8];
    const float* bz = (const float*)d_in[9];
    float* out = (float*)d_out;
    const size_t HN = (size_t)N_NODES * H;           // 4,194,304 elems
    const size_t H_BYTES = HN * 4;                   // 16 MiB
    const size_t W_BYTES = (72 + 24 + 128) * 2048;   // 448 KiB

    if (ws_size >= H_BYTES + W_BYTES) {
        // A (ws) and B (d_out scratch) hi/lo buffers; level 0 overwrites d_out f32
        short* A_hi = (short*)d_ws;
        short* A_lo = A_hi + HN;
        short* B_hi = (short*)d_out;
        short* B_lo = B_hi + HN;
        short* wsp  = (short*)((char*)d_ws + H_BYTES);

        grnn_prep<<<56, 256, 0, stream>>>(Wr, Wh, Wz, wsp);
        // level 15 (odd -> A)
        grnn_leaf_bf<<<(N_NODES * H) / BLK, BLK, 0, stream>>>(contents, Wu, bu, A_hi, A_lo);
        for (int k = 14; k >= 0; --k) {
            const short* in_hi = ((k + 1) & 1) ? A_hi : B_hi;   // buf(k+1)
            const short* in_lo = ((k + 1) & 1) ? A_lo : B_lo;
            short* out_hi = (k & 1) ? A_hi : B_hi;              // buf(k)
            short* out_lo = (k & 1) ? A_lo : B_lo;
            grnn_step_mfma<<<N_NODES / MT, BLK, 0, stream>>>(
                contents + (size_t)k * N_NODES * FEAT,
                children + (size_t)k * N_NODES * 2,
                in_hi, in_lo, Wu, bu, br, bh, bz, wsp,
                out_hi, out_lo, out, (k == 0) ? 1 : 0);
        }
    } else {
        float* h_ws = (float*)d_ws;
        grnn_leaf_kernel<<<(N_NODES * H) / BLK, BLK, 0, stream>>>(contents, Wu, bu, h_ws);
        for (int k = 14; k >= 0; --k) {
            const float* hin = (((k + 1) & 1) == 0) ? out : h_ws;
            float* hout = ((k & 1) == 0) ? out : h_ws;
            grnn_step_v1<<<N_NODES / NT1, BLK, 0, stream>>>(
                contents + (size_t)k * N_NODES * FEAT,
                children + (size_t)k * N_NODES * 2,
                hin, Wu, bu, Wr, br, Wh, bh, Wz, bz, hout);
        }
    }
}